// Round 5
// baseline (168.268 us; speedup 1.0000x reference)
//
#include <hip/hip_runtime.h>
#include <math.h>

#define N_TOT 8400
#define MASK_WORDS 132   // ceil(8400/64)
#define CAP 32           // max (word,bits) entries per row
#define RT 33            // rank tiles: ceil(8400/256)

typedef unsigned long long u64;

// monotone-increasing float->u32 mapping
__device__ __forceinline__ unsigned mono_u32(float f) {
    unsigned u = __float_as_uint(f);
    return (u & 0x80000000u) ? ~u : (u | 0x80000000u);
}

__device__ __forceinline__ u64 rl64(u64 v, int src) {
    unsigned lo = (unsigned)__builtin_amdgcn_readlane((int)(unsigned)v, src);
    unsigned hi = (unsigned)__builtin_amdgcn_readlane((int)(unsigned)(v >> 32), src);
    return ((u64)hi << 32) | (u64)lo;
}

// ---------------- K1: decode all 3 scales + build sort keys + zero-init state ----------------
__global__ void decode_kernel(const float* __restrict__ score0, const float* __restrict__ bbox0, const float* __restrict__ kps0,
                              const float* __restrict__ score1, const float* __restrict__ bbox1, const float* __restrict__ kps1,
                              const float* __restrict__ score2, const float* __restrict__ bbox2, const float* __restrict__ kps2,
                              float* __restrict__ logit, float* __restrict__ sig,
                              float* __restrict__ box, float* __restrict__ kps,
                              u64* __restrict__ key, int* __restrict__ rank,
                              unsigned int* __restrict__ cnt,
                              u64* __restrict__ validw, u64* __restrict__ rowflag) {
    int i = blockIdx.x * blockDim.x + threadIdx.x;
    if (i >= N_TOT) return;
    if (i < MASK_WORDS) { validw[i] = 0ull; rowflag[i] = 0ull; }
    rank[i] = 0;
    cnt[i] = 0u;
    const float *sc, *bb, *kp;
    int m, F; float s;
    if (i < 6400)      { sc = score0; bb = bbox0; kp = kps0; m = i;        F = 80; s = 8.f;  }
    else if (i < 8000) { sc = score1; bb = bbox1; kp = kps1; m = i - 6400; F = 40; s = 16.f; }
    else               { sc = score2; bb = bbox2; kp = kps2; m = i - 8000; F = 20; s = 32.f; }
    float px = (float)(m % F) * s;
    float py = (float)(m / F) * s;
    float lg = sc[m];
    logit[i] = lg;
    sig[i] = 1.0f / (1.0f + expf(-lg));
    // descending-logit order with ascending-index tie-break, as one u64 key (ascending)
    key[i] = ((u64)(~mono_u32(lg)) << 14) | (u64)i;
    float d0 = bb[m*4+0]*s, d1 = bb[m*4+1]*s, d2 = bb[m*4+2]*s, d3 = bb[m*4+3]*s;
    box[i*4+0] = px - d0;
    box[i*4+1] = py - d1;
    box[i*4+2] = px + d2;
    box[i*4+3] = py + d3;
    #pragma unroll
    for (int c = 0; c < 5; ++c) {
        kps[i*10 + 2*c]   = px + kp[m*10 + 2*c]   * s;
        kps[i*10 + 2*c+1] = py + kp[m*10 + 2*c+1] * s;
    }
}

// ---------------- K2: tiled rank = #{j : key[j] < key[i]} ----------------
__global__ __launch_bounds__(256) void rank_kernel(const u64* __restrict__ key, int* __restrict__ rank) {
    __shared__ u64 tile[256];
    int i = blockIdx.x * 256 + threadIdx.x;
    int t0 = blockIdx.y * 256;
    u64 ki = (i < N_TOT) ? key[i] : 0ull;
    int j = t0 + threadIdx.x;
    tile[threadIdx.x] = (j < N_TOT) ? key[j] : ~0ull;   // OOB sorts last (never < ki)
    __syncthreads();
    if (i >= N_TOT) return;
    int rk = 0;
    #pragma unroll 8
    for (int k = 0; k < 256; ++k) {
        rk += (tile[k] < ki) ? 1 : 0;
    }
    if (rk) atomicAdd(&rank[i], rk);
}

// ---------------- K3: scatter into sorted order + set valid bits ----------------
__global__ void scatter_kernel(const int* __restrict__ rank,
                               const float* __restrict__ logit, const float* __restrict__ sig,
                               const float* __restrict__ box, const float* __restrict__ kps,
                               float* __restrict__ s_logit, float* __restrict__ s_sig,
                               float* __restrict__ s_box, float* __restrict__ s_kps,
                               u64* __restrict__ validw) {
    int i = blockIdx.x * blockDim.x + threadIdx.x;
    if (i >= N_TOT) return;
    int r = rank[i];
    float lg = logit[i];
    s_logit[r] = lg;
    s_sig[r] = sig[i];
    #pragma unroll
    for (int c = 0; c < 4; ++c)  s_box[r*4+c] = box[i*4+c];
    #pragma unroll
    for (int c = 0; c < 10; ++c) s_kps[r*10+c] = kps[i*10+c];
    if (lg > 0.f) atomicOr(&validw[r >> 6], 1ull << (r & 63));
}

// ---------------- K4: sparse successor-overlap pairs (branch-free inner loop) ----------------
__global__ __launch_bounds__(64) void pairs_kernel(const float* __restrict__ s_logit,
                                                   const float* __restrict__ s_box,
                                                   unsigned int* __restrict__ cnt,
                                                   ulonglong2* __restrict__ ent,
                                                   u64* __restrict__ rowflag) {
    int cw = blockIdx.x;   // column word 0..131
    int rb = blockIdx.y;   // row block 0..131
    if (cw < rb) return;   // all j <= r in these blocks
    int tid = threadIdx.x;

    __shared__ float4 cbox[64];
    __shared__ float  carea[64];
    int j0 = cw * 64;
    int j = j0 + tid;
    float4 cb = make_float4(0.f, 0.f, 0.f, 0.f);
    float lgj = -1.f;
    if (j < N_TOT) {
        cb = ((const float4*)s_box)[j];
        lgj = s_logit[j];
    }
    cbox[tid] = cb;
    carea[tid] = (cb.z - cb.x) * (cb.w - cb.y);
    u64 cvalid = __ballot(j < N_TOT && lgj > 0.f);
    __syncthreads();
    if (cvalid == 0ull) return;     // no valid columns (sorted => ranks >= V)

    int r = rb * 64 + tid;
    float lgr = (r < N_TOT) ? s_logit[r] : -1.f;
    if (__ballot(lgr > 0.f) == 0ull) return;   // whole wave of invalid rows

    u64 bits = 0ull;
    if (lgr > 0.f) {
        float4 rb4 = ((const float4*)s_box)[r];
        float rarea = (rb4.z - rb4.x) * (rb4.w - rb4.y);
        #pragma unroll 4
        for (int k = 0; k < 64; ++k) {
            float4 c4 = cbox[k];
            float ltx = fmaxf(rb4.x, c4.x);
            float lty = fmaxf(rb4.y, c4.y);
            float rbx = fminf(rb4.z, c4.z);
            float rby = fminf(rb4.w, c4.w);
            float w = fmaxf(rbx - ltx, 0.f);
            float h = fmaxf(rby - lty, 0.f);
            float inter = w * h;
            float iou = inter / (rarea + carea[k] - inter + 1e-9f);
            bits |= (iou > 0.4f) ? (1ull << k) : 0ull;
        }
        u64 m = cvalid;                                  // only valid columns
        if (cw == rb) m &= (tid == 63) ? 0ull : (~0ull << (tid + 1));  // only strict successors
        bits &= m;
    }
    if (bits) {
        unsigned idx = atomicAdd(&cnt[r], 1u);
        if (idx < CAP) {
            ulonglong2 e; e.x = bits; e.y = (u64)cw;
            ent[(size_t)r * CAP + idx] = e;
        }
        atomicOr(&rowflag[r >> 6], 1ull << (r & 63));
    }
}

// ---------------- K5: apply-only greedy resolve (one wave) ----------------
// rem is an LDS bitmap. Per rank-word w: beta = validw & rowflag & ~rem[w] are the
// kept-rows-with-edges; only they act. Application is single-lane exec-masked LDS
// atomicOr of the lane's OWN preloaded entries (no readlane on the apply path).
// Intra-word edge targets (rare) patch beta via ballot + readlane.
__global__ __launch_bounds__(64) void nms_kernel(const u64* __restrict__ rowflag_g,
                                                 const u64* __restrict__ validw_g,
                                                 const unsigned int* __restrict__ cnt_g,
                                                 const ulonglong2* __restrict__ ent_g,
                                                 u64* __restrict__ keep_words) {
    __shared__ unsigned remlo[MASK_WORDS];
    __shared__ unsigned remhi[MASK_WORDS];
    int lane = threadIdx.x;

    // zero rem bitmap
    for (int w = lane; w < MASK_WORDS; w += 64) { remlo[w] = 0u; remhi[w] = 0u; }

    // register-distributed validw / rowflag (lane owns words lane, 64+lane, 128+lane)
    u64 vwreg[3], efreg[3];
    #pragma unroll
    for (int s = 0; s < 3; ++s) {
        int w = s * 64 + lane;
        vwreg[s] = (w < MASK_WORDS) ? validw_g[w] : 0ull;
        efreg[s] = (w < MASK_WORDS) ? rowflag_g[w] : 0ull;
    }

    // prefetch group 0 per-lane row data (row = w*64+lane)
    unsigned cntC = cnt_g[lane];
    ulonglong2 eAC = ent_g[(size_t)lane * CAP + 0];
    ulonglong2 eBC = ent_g[(size_t)lane * CAP + 1];

    for (int w = 0; w < MASK_WORDS; ++w) {
        // prefetch next group
        unsigned cntN = 0u;
        ulonglong2 eAN; eAN.x = 0ull; eAN.y = 0ull;
        ulonglong2 eBN; eBN.x = 0ull; eBN.y = 0ull;
        int rn = (w + 1) * 64 + lane;
        if (w + 1 < MASK_WORDS && rn < N_TOT) {
            cntN = cnt_g[rn];
            eAN = ent_g[(size_t)rn * CAP + 0];
            eBN = ent_g[(size_t)rn * CAP + 1];
        }

        int slot = w >> 6, owner = w & 63;
        u64 vw_s = rl64(vwreg[slot == 0 ? 0 : (slot == 1 ? 1 : 2)], owner);
        u64 ef_s = rl64(efreg[slot == 0 ? 0 : (slot == 1 ? 1 : 2)], owner);
        u64 b0 = vw_s & ef_s;
        if (b0) {
            // read current rem word (uniform address -> broadcast), make scalar
            unsigned rlo = remlo[w], rhi = remhi[w];
            rlo = (unsigned)__builtin_amdgcn_readfirstlane((int)rlo);
            rhi = (unsigned)__builtin_amdgcn_readfirstlane((int)rhi);
            u64 remw = ((u64)rhi << 32) | (u64)rlo;
            u64 beta = b0 & ~remw;
            u64 totpatch = 0ull;
            while (beta) {
                int i = __builtin_ctzll(beta); beta &= beta - 1;
                u64 patch = 0ull;                 // per-lane; nonzero only on lane i
                if (lane == i) {                  // single-lane apply, no readlane
                    unsigned c = cntC;
                    if (c > 0) {
                        int tw = (int)eAC.y;
                        if (tw == w) patch |= eAC.x;
                        else { atomicOr(&remlo[tw], (unsigned)eAC.x); atomicOr(&remhi[tw], (unsigned)(eAC.x >> 32)); }
                    }
                    if (c > 1) {
                        int tw = (int)eBC.y;
                        if (tw == w) patch |= eBC.x;
                        else { atomicOr(&remlo[tw], (unsigned)eBC.x); atomicOr(&remhi[tw], (unsigned)(eBC.x >> 32)); }
                    }
                    if (c > 2) {                  // rare overflow entries from global
                        unsigned cm = min(c, (unsigned)CAP);
                        int r = w * 64 + i;
                        for (unsigned e = 2; e < cm; ++e) {
                            ulonglong2 g = ent_g[(size_t)r * CAP + e];
                            int tw = (int)g.y;
                            if (tw == w) patch |= g.x;
                            else { atomicOr(&remlo[tw], (unsigned)g.x); atomicOr(&remhi[tw], (unsigned)(g.x >> 32)); }
                        }
                    }
                }
                u64 pball = __ballot(patch != 0ull);
                if (pball) {                      // rare intra-word target
                    u64 pb = rl64(patch, i);
                    beta &= ~pb;
                    totpatch |= pb;
                }
            }
            if (totpatch) {
                if (lane == 0) {
                    atomicOr(&remlo[w], (unsigned)totpatch);
                    atomicOr(&remhi[w], (unsigned)(totpatch >> 32));
                }
            }
        }
        cntC = cntN; eAC = eAN; eBC = eBN;
    }

    __syncthreads();   // single wave, but ensure LDS visibility for final read
    #pragma unroll
    for (int s = 0; s < 3; ++s) {
        int w = s * 64 + lane;
        if (w < MASK_WORDS) {
            u64 rem = ((u64)remhi[w] << 32) | (u64)remlo[w];
            keep_words[w] = vwreg[s] & ~rem;
        }
    }
}

// ---------------- K6: write outputs ----------------
__global__ void output_kernel(const float* __restrict__ s_sig, const float* __restrict__ s_box,
                              const float* __restrict__ s_kps,
                              const u64* __restrict__ keep_words,
                              float* __restrict__ out) {
    int r = blockIdx.x * blockDim.x + threadIdx.x;
    if (r >= N_TOT) return;
    float m = ((keep_words[r >> 6] >> (r & 63)) & 1ull) ? 1.0f : 0.0f;
    float* ob = out;                   // 8400*4
    float* os = out + 33600;           // 8400
    float* okp = out + 42000;          // 8400*10
    float* om = out + 126000;          // 8400
    #pragma unroll
    for (int c = 0; c < 4; ++c)  ob[r*4+c] = s_box[r*4+c] * m;
    os[r] = s_sig[r] * m;
    #pragma unroll
    for (int c = 0; c < 10; ++c) okp[r*10+c] = s_kps[r*10+c] * m;
    om[r] = m;
}

extern "C" void kernel_launch(void* const* d_in, const int* in_sizes, int n_in,
                              void* d_out, int out_size, void* d_ws, size_t ws_size,
                              hipStream_t stream) {
    const float *score0, *bbox0, *kps0, *score1, *bbox1, *kps1, *score2, *bbox2, *kps2;
    if (in_sizes[1] == 25600) {
        score0 = (const float*)d_in[0]; bbox0 = (const float*)d_in[1]; kps0 = (const float*)d_in[2];
        score1 = (const float*)d_in[3]; bbox1 = (const float*)d_in[4]; kps1 = (const float*)d_in[5];
        score2 = (const float*)d_in[6]; bbox2 = (const float*)d_in[7]; kps2 = (const float*)d_in[8];
    } else {
        score0 = (const float*)d_in[0]; score1 = (const float*)d_in[1]; score2 = (const float*)d_in[2];
        bbox0  = (const float*)d_in[3]; bbox1  = (const float*)d_in[4]; bbox2  = (const float*)d_in[5];
        kps0   = (const float*)d_in[6]; kps1   = (const float*)d_in[7]; kps2   = (const float*)d_in[8];
    }

    char* ws = (char*)d_ws;
    float* logit   = (float*)(ws + 0);
    float* sig     = (float*)(ws + 33600);
    float* box     = (float*)(ws + 67200);
    float* kps     = (float*)(ws + 201600);
    int*   rank    = (int*)  (ws + 537600);
    float* s_logit = (float*)(ws + 571200);
    float* s_sig   = (float*)(ws + 604800);
    float* s_box   = (float*)(ws + 638400);          // 16B-aligned (float4 loads)
    float* s_kps   = (float*)(ws + 772800);          // ends 1108800
    u64*   keep_words = (u64*)(ws + 1108800);        // 1056 B
    u64*   validw     = (u64*)(ws + 1110144);        // 1056 B
    u64*   rowflag    = (u64*)(ws + 1111296);        // 1056 B
    unsigned int* cnt = (unsigned int*)(ws + 1112448);   // 33600 B
    u64*   key        = (u64*)(ws + 1146368);            // 67200 B
    ulonglong2*   ent = (ulonglong2*)(ws + 1213568);     // 8400*32*16 = 4.3 MB

    float* out = (float*)d_out;

    decode_kernel<<<(N_TOT + 255) / 256, 256, 0, stream>>>(
        score0, bbox0, kps0, score1, bbox1, kps1, score2, bbox2, kps2,
        logit, sig, box, kps, key, rank, cnt, validw, rowflag);
    rank_kernel<<<dim3(RT, RT), 256, 0, stream>>>(key, rank);
    scatter_kernel<<<33, 256, 0, stream>>>(rank, logit, sig, box, kps,
                                           s_logit, s_sig, s_box, s_kps, validw);
    pairs_kernel<<<dim3(MASK_WORDS, MASK_WORDS), 64, 0, stream>>>(s_logit, s_box, cnt, ent, rowflag);
    nms_kernel<<<1, 64, 0, stream>>>(rowflag, validw, cnt, ent, keep_words);
    output_kernel<<<33, 256, 0, stream>>>(s_sig, s_box, s_kps, keep_words, out);
}